// Round 3
// baseline (2710.218 us; speedup 1.0000x reference)
//
#include <hip/hip_runtime.h>

#define NPTS   120000
#define NOFF   28      // 27 neighbor offsets + 1 point-transform slot
#define CHUNKS 7       // 448 / 64

typedef __bf16 bf16;
typedef __bf16 bf16x8 __attribute__((ext_vector_type(8)));
typedef float  f32x4  __attribute__((ext_vector_type(4)));

// ---------------- weight prep: pack (Wz|Wr) -> WB1, per-lane fragment order:
// tid = (((koff*7+ch)*2 + kk)*16 + n16)*64 + lane
// value[j] = W[k = ch*64 + (kk*4 + lane>>4)*8 + j][n = n16*16 + (lane&15)]
__global__ void wprep1(const float* __restrict__ Wz, const float* __restrict__ Wzp,
                       const float* __restrict__ Wr, const float* __restrict__ Wrp,
                       bf16* __restrict__ WB1)
{
    int tid  = blockIdx.x * 256 + threadIdx.x;   // 1568 * 256 = 401408
    int lane = tid & 63;
    int n16  = (tid >> 6) & 15;
    int kk   = (tid >> 10) & 1;
    int chk  = tid >> 11;            // koff*7 + ch, 0..195
    int koff = chk / 7, ch = chk % 7;
    int n    = n16 * 16 + (lane & 15);
    int k0   = ch * 64 + (kk * 4 + (lane >> 4)) * 8;
    bf16x8 v;
    #pragma unroll
    for (int j = 0; j < 8; ++j) {
        int cin = k0 + j;
        float w;
        if (koff < 27) w = (n < 128) ? Wz[((long)koff*448 + cin)*128 + n]
                                     : Wr[((long)koff*448 + cin)*128 + (n-128)];
        else           w = (n < 128) ? Wzp[(long)cin*128 + n]
                                     : Wrp[(long)cin*128 + (n-128)];
        v[j] = (bf16)w;
    }
    *(bf16x8*)(WB1 + (long)tid * 8) = v;
}

// ---------------- weight prep: pack Wq -> WB2 (NCOLS=128, n16 in 0..7)
__global__ void wprep2(const float* __restrict__ Wq, const float* __restrict__ Wqp,
                       bf16* __restrict__ WB2)
{
    int tid  = blockIdx.x * 256 + threadIdx.x;   // 784 * 256 = 200704
    int lane = tid & 63;
    int n16  = (tid >> 6) & 7;
    int kk   = (tid >> 9) & 1;
    int chk  = tid >> 10;            // koff*7 + ch
    int koff = chk / 7, ch = chk % 7;
    int n    = n16 * 16 + (lane & 15);
    int k0   = ch * 64 + (kk * 4 + (lane >> 4)) * 8;
    bf16x8 v;
    #pragma unroll
    for (int j = 0; j < 8; ++j) {
        int cin = k0 + j;
        float w = (koff < 27) ? Wq[((long)koff*448 + cin)*128 + n]
                              : Wqp[(long)cin*128 + n];
        v[j] = (bf16)w;
    }
    *(bf16x8*)(WB2 + (long)tid * 8) = v;
}

// ---------------- feature prep: F1 = bf16([h|x]), 8 cols/thread
__global__ void fprep(const float* __restrict__ h, const float* __restrict__ x,
                      bf16* __restrict__ F1)
{
    long g = (long)blockIdx.x * blockDim.x + threadIdx.x;
    if (g >= (long)NPTS * 56) return;
    int p = (int)(g / 56);
    int c = (int)(g % 56) * 8;
    const float* src = (c < 128) ? h + (long)p*128 + c : x + (long)p*320 + (c-128);
    float4 a = ((const float4*)src)[0];
    float4 b = ((const float4*)src)[1];
    bf16x8 v;
    v[0]=(bf16)a.x; v[1]=(bf16)a.y; v[2]=(bf16)a.z; v[3]=(bf16)a.w;
    v[4]=(bf16)b.x; v[5]=(bf16)b.y; v[6]=(bf16)b.z; v[7]=(bf16)b.w;
    *(bf16x8*)(F1 + (long)p*448 + c) = v;
}

// ---------------- barrier-free register gather-GEMM.
// Wave = 64x64 tile, MW x NW waves per block. No LDS, no __syncthreads.
// A frags gathered per-lane from F rows; B frags are 1KB contiguous packed loads.
// Register double-buffer with literal parity (koff-pair loop, 7 chunks odd).

#define LOADA(BUF, CH)                                                        \
    _Pragma("unroll")                                                         \
    for (int mi = 0; mi < 4; ++mi) {                                          \
        const bf16* base_;                                                    \
        if (GATE == 2 && (CH) < 2) base_ = pa2g[mi] + (CH) * 64;              \
        else                       base_ = pa1[mi] + (CH) * 64;               \
        af[BUF][mi][0] = *(const bf16x8*)(base_);                             \
        af[BUF][mi][1] = *(const bf16x8*)(base_ + 32);                        \
    }

#define LOADB(BUF, KOFF, CH)                                                  \
    {                                                                         \
        const bf16x8* p_ = WBv + (((long)((KOFF)*7 + (CH)) * 2) * N16 + wn4) * 64 + lane; \
        _Pragma("unroll")                                                     \
        for (int kk = 0; kk < 2; ++kk)                                        \
            _Pragma("unroll")                                                 \
            for (int ni = 0; ni < 4; ++ni)                                    \
                bfr[BUF][ni][kk] = p_[(kk * N16 + ni) * 64];                  \
    }

#define STEP(CUR, KOFF, CH, IDXN)                                             \
    {                                                                         \
        if ((CH) < CHUNKS - 1) { LOADA((CUR)^1, (CH)+1); LOADB((CUR)^1, (KOFF), (CH)+1); } \
        else if ((KOFF) < NOFF - 1) { setup(IDXN); LOADA((CUR)^1, 0); LOADB((CUR)^1, (KOFF)+1, 0); } \
        _Pragma("unroll")                                                     \
        for (int kk = 0; kk < 2; ++kk)                                        \
            _Pragma("unroll")                                                 \
            for (int mi = 0; mi < 4; ++mi)                                    \
                _Pragma("unroll")                                             \
                for (int ni = 0; ni < 4; ++ni)                                \
                    acc[mi][ni] = __builtin_amdgcn_mfma_f32_16x16x32_bf16(    \
                        af[CUR][mi][kk], bfr[CUR][ni][kk], acc[mi][ni], 0, 0, 0); \
    }

template<int MW, int NW, int GATE>
__global__ __launch_bounds__(MW * NW * 64, 2)
void gconv_reg(const bf16* __restrict__ F, const bf16* __restrict__ f2,
               const int* __restrict__ nbr, const bf16* __restrict__ WB,
               const float* __restrict__ b0, const float* __restrict__ b1,
               const float* __restrict__ hbuf, float* __restrict__ zbuf,
               bf16* __restrict__ f2out, float* __restrict__ out,
               const bf16* __restrict__ zrow)
{
    constexpr int N16 = NW * 64 / 16;
    const int t    = threadIdx.x;
    const int lane = t & 63;
    const int w    = t >> 6;
    const int wm   = w % MW;
    const int wn   = w / MW;
    const int wn4  = wn * 4;
    const int mbase = blockIdx.x * (MW * 64) + wm * 64;
    const int l15  = lane & 15, lq = lane >> 4;
    const int lrow = mbase + lane;          // row whose nbr-index this lane fetches

    const bf16x8* WBv = (const bf16x8*)WB;

    f32x4 acc[4][4];
    #pragma unroll
    for (int i = 0; i < 4; ++i)
        #pragma unroll
        for (int j = 0; j < 4; ++j)
            acc[i][j] = {0.f, 0.f, 0.f, 0.f};

    const bf16* pa1[4];
    const bf16* pa2g[4];

    auto setup = [&](int idx) {
        #pragma unroll
        for (int mi = 0; mi < 4; ++mi) {
            int r = __shfl(idx, mi * 16 + l15);
            pa1[mi] = (r >= 0 ? F + (long)r * 448 : zrow) + lq * 8;
            if constexpr (GATE == 2)
                pa2g[mi] = (r >= 0 ? f2 + (long)r * 128 : zrow) + lq * 8;
        }
    };

    bf16x8 af[2][4][2], bfr[2][4][2];

    int idx0 = (lrow < NPTS) ? nbr[(long)lrow * 27] : -1;
    setup(idx0);
    LOADA(0, 0); LOADB(0, 0, 0);

    for (int kp = 0; kp < NOFF / 2; ++kp) {
        const int k0 = 2 * kp, k1 = 2 * kp + 1;
        int idxN0 = -1, idxN1 = -1;
        if (lrow < NPTS) idxN0 = (k0 + 1 == 27) ? lrow : nbr[(long)lrow * 27 + k0 + 1];
        STEP(0, k0, 0, idxN0) STEP(1, k0, 1, idxN0) STEP(0, k0, 2, idxN0)
        STEP(1, k0, 3, idxN0) STEP(0, k0, 4, idxN0) STEP(1, k0, 5, idxN0)
        STEP(0, k0, 6, idxN0)
        if (k1 < 27 && lrow < NPTS) idxN1 = nbr[(long)lrow * 27 + k1 + 1];
        STEP(1, k1, 0, idxN1) STEP(0, k1, 1, idxN1) STEP(1, k1, 2, idxN1)
        STEP(0, k1, 3, idxN1) STEP(1, k1, 4, idxN1) STEP(0, k1, 5, idxN1)
        STEP(1, k1, 6, idxN1)
    }

    // epilogue: C/D layout col=lane&15, row=(lane>>4)*4+reg  [m89/m91]
    #pragma unroll
    for (int mi = 0; mi < 4; ++mi) {
        int rb = mi * 16 + lq * 4;
        #pragma unroll
        for (int ni = 0; ni < 4; ++ni) {
            int c = wn * 64 + ni * 16 + l15;
            f32x4 v = acc[mi][ni];
            #pragma unroll
            for (int rg = 0; rg < 4; ++rg) {
                int p = mbase + rb + rg;
                if (p < NPTS) {
                    float pre = v[rg];
                    if constexpr (GATE == 1) {
                        if (c < 128) {
                            float z = 1.f / (1.f + __expf(-(pre + b0[c])));
                            zbuf[(long)p * 128 + c] = z;
                        } else {
                            int cc = c - 128;
                            float r = 1.f / (1.f + __expf(-(pre + b1[cc])));
                            f2out[(long)p * 128 + cc] = (bf16)(r * hbuf[(long)p * 128 + cc]);
                        }
                    } else {
                        float q  = tanhf(pre + b0[c]);
                        float z  = zbuf[(long)p * 128 + c];
                        float hv = hbuf[(long)p * 128 + c];
                        out[(long)p * 128 + c] = (1.f - z) * hv + z * q;
                    }
                }
            }
        }
    }
}

extern "C" void kernel_launch(void* const* d_in, const int* in_sizes, int n_in,
                              void* d_out, int out_size, void* d_ws, size_t ws_size,
                              hipStream_t stream)
{
    const float* h   = (const float*)d_in[0];
    const float* x   = (const float*)d_in[1];
    const int*   nbr = (const int*)d_in[2];
    const float* Wz  = (const float*)d_in[3];
    const float* Wzp = (const float*)d_in[4];
    const float* bz  = (const float*)d_in[5];
    const float* Wr  = (const float*)d_in[6];
    const float* Wrp = (const float*)d_in[7];
    const float* br  = (const float*)d_in[8];
    const float* Wq  = (const float*)d_in[9];
    const float* Wqp = (const float*)d_in[10];
    const float* bq  = (const float*)d_in[11];
    float* out = (float*)d_out;

    char* ws = (char*)d_ws;
    bf16* WB1 = (bf16*)ws;  ws += (size_t)401408 * 8 * 2;       // 6.42 MB
    bf16* WB2 = (bf16*)ws;  ws += (size_t)200704 * 8 * 2;       // 3.21 MB
    bf16* F1  = (bf16*)ws;  ws += (size_t)NPTS * 448 * 2;       // 107.5 MB
    bf16* F2  = (bf16*)ws;  ws += (size_t)NPTS * 128 * 2;       // 30.7 MB  (r*h)
    bf16* zrow = (bf16*)ws; ws += 1024;                          // zero row
    float* zbuf = out;  // z stored in d_out (fp32), overwritten by pass 2

    hipMemsetAsync(zrow, 0, 1024, stream);
    wprep1<<<1568, 256, 0, stream>>>(Wz, Wzp, Wr, Wrp, WB1);
    wprep2<<<784, 256, 0, stream>>>(Wq, Wqp, WB2);
    long groups = (long)NPTS * 56;
    fprep<<<(int)((groups + 255) / 256), 256, 0, stream>>>(h, x, F1);

    // pass 1: 128 rows x 256 cols (z|r) per block, 8 waves
    gconv_reg<2, 4, 1><<<(NPTS + 127) / 128, 512, 0, stream>>>(
        F1, nullptr, nbr, WB1, bz, br, h, zbuf, F2, nullptr, zrow);
    // pass 2: 256 rows x 128 cols (q) per block, 8 waves
    gconv_reg<4, 2, 2><<<(NPTS + 255) / 256, 512, 0, stream>>>(
        F1, F2, nbr, WB2, bq, nullptr, h, zbuf, nullptr, out, zrow);
}